// Round 1
// baseline (1307.184 us; speedup 1.0000x reference)
//
#include <hip/hip_runtime.h>
#include <hip/hip_bf16.h>

#define BB 256
#define LL 1024
#define EE 128
#define HH 256
#define VV 64

// ws layout (floats):
//   [0      .. 16384)  table[v][i] = dot(embedding[v,:], W_e[i,:]) + b_e[i] + b_h[i]
//   [16384  .. 81920)  Wt[c][i]    = W_h[i][c]      (transposed, 256x256)
//   [81920  .. 98304)  fcT[c][v]   = fc_w[v][c]     (transposed, 256x64)

__global__ void prep_kernel(const float* __restrict__ emb,
                            const float* __restrict__ W_e,
                            const float* __restrict__ b_e,
                            const float* __restrict__ W_h,
                            const float* __restrict__ b_h,
                            const float* __restrict__ fc_w,
                            float* __restrict__ ws) {
    int tid = blockIdx.x * blockDim.x + threadIdx.x;  // 0..65535
    // W_h transpose: Wt[c][i] = W_h[i][c]
    ws[16384 + tid] = W_h[(tid & 255) * 256 + (tid >> 8)];
    if (tid < 16384) {
        // fc_w transpose: fcT[c][v] = fc_w[v][c]
        ws[81920 + tid] = fc_w[(tid & 63) * 256 + (tid >> 6)];
        // table
        int v = tid >> 8, i = tid & 255;
        float s = b_e[i] + b_h[i];
        const float* ev = emb + v * EE;
        const float* wr = W_e + i * EE;
#pragma unroll 8
        for (int e = 0; e < EE; ++e) s = fmaf(ev[e], wr[e], s);
        ws[tid] = s;
    }
}

__launch_bounds__(512, 2)
__global__ void rnn_kernel(const int* __restrict__ x,
                           const float* __restrict__ hidden,
                           const float* __restrict__ fc_b,
                           const float* __restrict__ ws,
                           float* __restrict__ out) {
    __shared__ float table[VV * HH];   // 64 KB
    __shared__ float h_lds[HH];        // 1 KB
    __shared__ float p_h[2][HH];       // 2 KB
    __shared__ float p_l[8][VV];       // 2 KB
    __shared__ int   x_lds[LL];        // 4 KB

    const int tid = threadIdx.x;
    const int b   = blockIdx.x;
    const int i   = tid & 255;   // matvec output index
    const int g   = tid >> 8;    // 0/1 : K-half
    const int v   = tid & 63;    // logits output index
    const int g3  = tid >> 6;    // 0..7 : logits K-slice

    // ---- prologue: stage x row, table; load weights into registers ----
    for (int q = tid; q < LL; q += 512) x_lds[q] = x[b * LL + q];
    for (int q = tid; q < VV * HH; q += 512) table[q] = ws[q];

    float W[128];
    const float* Wt = ws + 16384;
#pragma unroll
    for (int jj = 0; jj < 128; ++jj) W[jj] = Wt[(g * 128 + jj) * 256 + i];

    float fc[32];
    const float* fcT = ws + 81920;
#pragma unroll
    for (int k = 0; k < 32; ++k) fc[k] = fcT[(g3 * 32 + k) * 64 + v];

    if (tid < HH) h_lds[tid] = hidden[b * HH + tid];
    __syncthreads();

    float* outL = out;                            // logits [B][L][V]
    float* outH = out + (size_t)BB * LL * VV;     // final hidden [B][H]

    // iteration t: matvec produces h_t (output index t) from h in LDS;
    // logits for output index t-1 read the same h (== h_{t-1}'s successor state).
    for (int t = 0; t <= LL; ++t) {
        float a0 = 0.f, a1 = 0.f, a2 = 0.f, a3 = 0.f;
        if (t < LL) {
            const float4* h4 = (const float4*)(h_lds + g * 128);
#pragma unroll
            for (int q = 0; q < 32; ++q) {
                float4 hv = h4[q];
                a0 = fmaf(W[4 * q + 0], hv.x, a0);
                a1 = fmaf(W[4 * q + 1], hv.y, a1);
                a2 = fmaf(W[4 * q + 2], hv.z, a2);
                a3 = fmaf(W[4 * q + 3], hv.w, a3);
            }
        }
        float l0 = 0.f, l1 = 0.f, l2 = 0.f, l3 = 0.f;
        if (t > 0) {
            const float4* hl = (const float4*)(h_lds + g3 * 32);
#pragma unroll
            for (int q = 0; q < 8; ++q) {
                float4 hv = hl[q];
                l0 = fmaf(fc[4 * q + 0], hv.x, l0);
                l1 = fmaf(fc[4 * q + 1], hv.y, l1);
                l2 = fmaf(fc[4 * q + 2], hv.z, l2);
                l3 = fmaf(fc[4 * q + 3], hv.w, l3);
            }
        }
        if (t < LL) p_h[g][i] = (a0 + a1) + (a2 + a3);
        if (t > 0)  p_l[g3][v] = (l0 + l1) + (l2 + l3);
        __syncthreads();

        if (t < LL && tid < HH) {
            float s = p_h[0][tid] + p_h[1][tid] + table[x_lds[t] * HH + tid];
            h_lds[tid] = tanhf(s);
        }
        if (t > 0 && tid >= 256 && tid < 320) {
            int vv = tid - 256;
            float s = fc_b[vv];
#pragma unroll
            for (int q = 0; q < 8; ++q) s += p_l[q][vv];
            outL[((size_t)b * LL + (t - 1)) * VV + vv] = s;
        }
        __syncthreads();
    }

    if (tid < HH) outH[b * HH + tid] = h_lds[tid];
}

extern "C" void kernel_launch(void* const* d_in, const int* in_sizes, int n_in,
                              void* d_out, int out_size, void* d_ws, size_t ws_size,
                              hipStream_t stream) {
    const int*   x      = (const int*)  d_in[0];
    const float* hidden = (const float*)d_in[1];
    const float* emb    = (const float*)d_in[2];
    const float* W_e    = (const float*)d_in[3];
    const float* b_e    = (const float*)d_in[4];
    const float* W_h    = (const float*)d_in[5];
    const float* b_h    = (const float*)d_in[6];
    const float* fc_w   = (const float*)d_in[7];
    const float* fc_b   = (const float*)d_in[8];
    float* out = (float*)d_out;
    float* ws  = (float*)d_ws;

    prep_kernel<<<256, 256, 0, stream>>>(emb, W_e, b_e, W_h, b_h, fc_w, ws);
    rnn_kernel<<<BB, 512, 0, stream>>>(x, hidden, fc_b, ws, out);
}

// Round 2
// 1284.070 us; speedup vs baseline: 1.0180x; 1.0180x over previous
//
#include <hip/hip_runtime.h>
#include <hip/hip_bf16.h>

#define BB 256
#define LL 1024
#define EE 128
#define HH 256
#define VV 64

typedef float v2f __attribute__((ext_vector_type(2)));
typedef float v4f __attribute__((ext_vector_type(4)));

// ws layout (floats):
//   [0      .. 16384)  table[v][i] = dot(emb[v,:], W_e[i,:]) + b_e[i] + b_h[i]
//   [16384  .. 81920)  W2: float2[p*1024 + tid] = {W_h[j][ks+2p], W_h[j][ks+2p+1]}
//                      j = 16*(tid>>6) + (tid&15), ks = 64*((tid&63)>>4), p=0..31
//   [81920  .. 98304)  F2: float2[p*1024 + tid] = {fc_w[v][k0+2p], fc_w[v][k0+2p+1]}
//                      v = 4*(tid>>6) + (tid&3), k0 = 16*((tid&63)>>2), p=0..7

__global__ void prep_kernel(const float* __restrict__ emb,
                            const float* __restrict__ W_e,
                            const float* __restrict__ b_e,
                            const float* __restrict__ W_h,
                            const float* __restrict__ b_h,
                            const float* __restrict__ fc_w,
                            float* __restrict__ ws) {
    int t = blockIdx.x * blockDim.x + threadIdx.x;  // 0..65535
    if (t < 32768) {  // W2
        int p = t >> 10, rt = t & 1023;
        int l = rt & 63;
        int j = 16 * (rt >> 6) + (l & 15);
        int ks = 64 * (l >> 4);
        float2 val;
        val.x = W_h[j * HH + ks + 2 * p];
        val.y = W_h[j * HH + ks + 2 * p + 1];
        ((float2*)(ws + 16384))[t] = val;
    }
    if (t < 8192) {  // F2
        int p = t >> 10, rt = t & 1023;
        int l = rt & 63;
        int v = 4 * (rt >> 6) + (l & 3);
        int k0 = 16 * (l >> 2);
        float2 val;
        val.x = fc_w[v * HH + k0 + 2 * p];
        val.y = fc_w[v * HH + k0 + 2 * p + 1];
        ((float2*)(ws + 81920))[t] = val;
    }
    if (t < 16384) {  // table
        int v = t >> 8, i = t & 255;
        const v4f* ev = (const v4f*)(emb + v * EE);
        const v4f* wr = (const v4f*)(W_e + i * EE);
        float s = b_e[i] + b_h[i];
#pragma unroll 8
        for (int e = 0; e < EE / 4; ++e) {
            v4f a = ev[e], c = wr[e];
            s += a.x * c.x + a.y * c.y + a.z * c.z + a.w * c.w;
        }
        ws[t] = s;
    }
}

__device__ __forceinline__ void pkfma(v2f& acc, v2f a, v2f b) {
    asm("v_pk_fma_f32 %0, %1, %2, %0" : "+v"(acc) : "v"(a), "v"(b));
}

__device__ __forceinline__ float tanh_fast(float x) {
    float a = fabsf(x);
    float e = __expf(-2.0f * a);
    float r = (1.0f - e) * __builtin_amdgcn_rcpf(1.0f + e);
    return copysignf(r, x);
}

// padded h layout: element i lives at 20*(i>>4) + (i&15)  (16 groups of 16, pad 4)
__launch_bounds__(1024)
__global__ void rnn_kernel(const int* __restrict__ x,
                           const float* __restrict__ hidden,
                           const float* __restrict__ fc_b,
                           const float* __restrict__ ws,
                           float* __restrict__ out) {
    __shared__ __align__(16) float table_l[VV * HH];  // 64 KB
    __shared__ __align__(16) float h_p[2][320];       // 2.5 KB padded double buffer
    __shared__ int x_l[LL];                           // 4 KB

    const int tid = threadIdx.x;
    const int b = blockIdx.x;
    const int w = tid >> 6;   // wave 0..15
    const int l = tid & 63;   // lane

    // ---- prologue staging ----
    {
        const v4f* src = (const v4f*)ws;
        v4f* dst = (v4f*)table_l;
#pragma unroll
        for (int k = 0; k < 4; ++k) dst[tid + 1024 * k] = src[tid + 1024 * k];
    }
    x_l[tid] = x[b * LL + tid];
    if (tid < HH) h_p[0][20 * (tid >> 4) + (tid & 15)] = hidden[b * HH + tid];

    v2f W2[32];
    {
        const v2f* p = (const v2f*)(ws + 16384);
#pragma unroll
        for (int q = 0; q < 32; ++q) W2[q] = p[q * 1024 + tid];
    }
    v2f F2[8];
    {
        const v2f* p = (const v2f*)(ws + 81920);
#pragma unroll
        for (int q = 0; q < 8; ++q) F2[q] = p[q * 1024 + tid];
    }
    const float fcb = fc_b[4 * w + (l & 3)];

    const int mbase = 80 * (l >> 4);   // matvec: lane's 64-chunk base (padded floats)
    const int lbase = 20 * (l >> 2);   // logits: lane's 16-chunk base
    const int xpi = 16 * w + l;        // (only lanes l<16 use it)
    float* outL = out + (size_t)b * LL * VV + 4 * w + (l & 3);

    __syncthreads();

    // xp pipeline: xp_cur = table row x[t] value for this lane's output
    float xp_cur = 0.f;
    int xv_next;
    {
        int xv0 = x_l[0];
        if (l < 16) xp_cur = table_l[xv0 * HH + xpi];
        xv_next = x_l[1];
    }

    float lbuf[8];
#pragma unroll 1
    for (int tb = 0; tb < LL; tb += 8) {
#pragma unroll
        for (int u = 0; u < 8; ++u) {
            const int t = tb + u;
            const float* hr = h_p[u & 1];        // h_{t-1}
            float* hw = h_p[(u + 1) & 1];        // h_t

            // prefetch next-step xp and next-next x id (off critical path)
            float xp_n = 0.f;
            if (l < 16) xp_n = table_l[xv_next * HH + xpi];
            const int xv_nn = x_l[(t + 2) & (LL - 1)];

            // ---- matvec partial: 64-chunk of h against W slice ----
            v2f accA = {0.f, 0.f}, accB = {0.f, 0.f};
#pragma unroll
            for (int q = 0; q < 16; ++q) {
                v4f hv = *(const v4f*)(hr + mbase + 20 * (q >> 2) + 4 * (q & 3));
                pkfma(accA, W2[2 * q], hv.lo);
                pkfma(accB, W2[2 * q + 1], hv.hi);
            }

            // ---- logits for step t-1 (reads same hr) ----
            if (t > 0) {
                v2f lacc = {0.f, 0.f};
#pragma unroll
                for (int p = 0; p < 4; ++p) {
                    v4f hv = *(const v4f*)(hr + lbase + 4 * p);
                    pkfma(lacc, F2[2 * p], hv.lo);
                    pkfma(lacc, F2[2 * p + 1], hv.hi);
                }
                float g = lacc.x + lacc.y;
                g += __shfl_xor(g, 4);
                g += __shfl_xor(g, 8);
                g += __shfl_xor(g, 16);
                g += __shfl_xor(g, 32);
                lbuf[(u + 7) & 7] = g + fcb;
            }

            // flush previous 8 steps' logits once per group
            if (u == 0 && tb > 0) {
                if (l < 4) {
#pragma unroll
                    for (int k = 0; k < 8; ++k)
                        outL[(size_t)(tb - 8 + k) * VV] = lbuf[k];
                }
            }

            // ---- reduce matvec, tanh, write h_t ----
            {
                float s = (accA.x + accA.y) + (accB.x + accB.y);
                s += __shfl_xor(s, 16);
                s += __shfl_xor(s, 32);
                if (l < 16) {
                    float hn = tanh_fast(s + xp_cur);
                    hw[20 * w + l] = hn;
                }
            }
            xp_cur = xp_n;
            xv_next = xv_nn;
            __syncthreads();
        }
    }

    // ---- epilogue: logits for step LL-1 from h_p[0]; final hidden ----
    {
        const float* hr = h_p[0];
        v2f lacc = {0.f, 0.f};
#pragma unroll
        for (int p = 0; p < 4; ++p) {
            v4f hv = *(const v4f*)(hr + lbase + 4 * p);
            pkfma(lacc, F2[2 * p], hv.lo);
            pkfma(lacc, F2[2 * p + 1], hv.hi);
        }
        float g = lacc.x + lacc.y;
        g += __shfl_xor(g, 4);
        g += __shfl_xor(g, 8);
        g += __shfl_xor(g, 16);
        g += __shfl_xor(g, 32);
        lbuf[7] = g + fcb;
        if (l < 4) {
#pragma unroll
            for (int k = 0; k < 8; ++k)
                outL[(size_t)(LL - 8 + k) * VV] = lbuf[k];
        }
        if (tid < HH)
            out[(size_t)BB * LL * VV + b * HH + tid] = h_p[0][20 * (tid >> 4) + (tid & 15)];
    }
}

extern "C" void kernel_launch(void* const* d_in, const int* in_sizes, int n_in,
                              void* d_out, int out_size, void* d_ws, size_t ws_size,
                              hipStream_t stream) {
    const int*   x      = (const int*)  d_in[0];
    const float* hidden = (const float*)d_in[1];
    const float* emb    = (const float*)d_in[2];
    const float* W_e    = (const float*)d_in[3];
    const float* b_e    = (const float*)d_in[4];
    const float* W_h    = (const float*)d_in[5];
    const float* b_h    = (const float*)d_in[6];
    const float* fc_w   = (const float*)d_in[7];
    const float* fc_b   = (const float*)d_in[8];
    float* out = (float*)d_out;
    float* ws  = (float*)d_ws;

    prep_kernel<<<256, 256, 0, stream>>>(emb, W_e, b_e, W_h, b_h, fc_w, ws);
    rnn_kernel<<<BB, 1024, 0, stream>>>(x, hidden, fc_b, ws, out);
}

// Round 3
// 791.646 us; speedup vs baseline: 1.6512x; 1.6220x over previous
//
#include <hip/hip_runtime.h>
#include <hip/hip_bf16.h>

#define BB 256
#define LL 1024
#define EE 128
#define HH 256
#define VV 64

typedef short bf16x8 __attribute__((ext_vector_type(8)));
typedef float f32x4 __attribute__((ext_vector_type(4)));

// ws layout (bytes):
//   [0,      65536)   table f32 [64][256]: b_e[j]+b_h[j]+dot(emb[v],W_e[j])
//   [65536, 196608)   W_h B-frags bf16: frag f=nt*8+kt (nt<16,kt<8), 1024B each,
//                     elem (l,i) = W_h[16nt+(l&15)][32kt+8*(l>>4)+i]
//   [196608,229376)   fc hi frags (nt<4): fc_w[16nt+(l&15)][32kt+8*(l>>4)+i] hi
//   [229376,262144)   fc lo frags (residual)

__device__ __forceinline__ unsigned short f2bf(float v) {
    __hip_bfloat16 h = __float2bfloat16(v);
    return *reinterpret_cast<unsigned short*>(&h);
}
__device__ __forceinline__ float bf2f(unsigned short u) {
    __hip_bfloat16 h = *reinterpret_cast<__hip_bfloat16*>(&u);
    return __bfloat162float(h);
}

__global__ void prep_kernel(const float* __restrict__ emb,
                            const float* __restrict__ W_e,
                            const float* __restrict__ b_e,
                            const float* __restrict__ W_h,
                            const float* __restrict__ b_h,
                            const float* __restrict__ fc_w,
                            float* __restrict__ ws) {
    int t = blockIdx.x * 256 + threadIdx.x;  // 0..26623
    if (t < 16384) {
        int v = t >> 8, j = t & 255;
        float s = b_e[j] + b_h[j];
        const float* ev = emb + v * EE;
        const float* wr = W_e + j * EE;
#pragma unroll 8
        for (int e = 0; e < EE; ++e) s = fmaf(ev[e], wr[e], s);
        ws[t] = s;
    } else if (t < 24576) {
        int q = t - 16384;            // 0..8191
        int f = q >> 6, l = q & 63;   // frag id, lane
        int nt = f >> 3, kt = f & 7;
        int row = 16 * nt + (l & 15);
        int k0 = 32 * kt + 8 * (l >> 4);
        unsigned short* p = (unsigned short*)((char*)ws + 65536 + f * 1024 + l * 16);
#pragma unroll
        for (int i = 0; i < 8; ++i) p[i] = f2bf(W_h[row * HH + k0 + i]);
    } else {
        int q = t - 24576;            // 0..2047
        int f = q >> 6, l = q & 63;   // frag id (nt<4), lane
        int nt = f >> 3, kt = f & 7;
        int row = 16 * nt + (l & 15); // v index
        int k0 = 32 * kt + 8 * (l >> 4);
        unsigned short* ph = (unsigned short*)((char*)ws + 196608 + f * 1024 + l * 16);
        unsigned short* pl = (unsigned short*)((char*)ws + 229376 + f * 1024 + l * 16);
#pragma unroll
        for (int i = 0; i < 8; ++i) {
            float v = fc_w[row * HH + k0 + i];
            unsigned short hi = f2bf(v);
            float res = v - bf2f(hi);
            ph[i] = hi;
            pl[i] = f2bf(res);
        }
    }
}

__device__ __forceinline__ float tanh_fast(float x) {
    float a = fabsf(x);
    float e = __expf(-2.0f * a);
    float r = (1.0f - e) * __builtin_amdgcn_rcpf(1.0f + e);
    return copysignf(r, x);
}

__launch_bounds__(384, 1)
__global__ void rnn_kernel(const int* __restrict__ x,
                           const float* __restrict__ hidden,
                           const float* __restrict__ fc_b,
                           const float* __restrict__ ws,
                           float* __restrict__ out) {
    __shared__ __align__(16) unsigned short hb[2][HH];  // bf16 h, double buffered

    const int tid = threadIdx.x;
    const int b = blockIdx.x;
    const int w = tid >> 6;      // wave 0..5
    const int l = tid & 63;

    const char* wsB  = (const char*)ws + 65536;
    const char* wsFH = (const char*)ws + 196608;
    const char* wsFL = (const char*)ws + 229376;
    const float* table = ws;

    float* outL = out;                          // [B][L][V]
    float* outH = out + (size_t)BB * LL * VV;   // [B][H]

    // stage initial hidden as bf16
    if (tid < HH) hb[0][tid] = f2bf(hidden[b * HH + tid]);

    if (w < 4) {
        // ---------------- matvec role: nt = 4w..4w+3 ----------------
        bf16x8 Bf[4][8];
#pragma unroll
        for (int nt2 = 0; nt2 < 4; ++nt2)
#pragma unroll
            for (int kt = 0; kt < 8; ++kt)
                Bf[nt2][kt] = *(const bf16x8*)(wsB + (((4 * w + nt2) * 8 + kt) * 1024) + l * 16);

        bf16x8 a[8];
        bf16x8 zz = {0, 0, 0, 0, 0, 0, 0, 0};
#pragma unroll
        for (int kt = 0; kt < 8; ++kt) a[kt] = zz;

        float xp[4];
        int xv_nn;
        {
            int xv0 = x[b * LL];
#pragma unroll
            for (int nt2 = 0; nt2 < 4; ++nt2)
                xp[nt2] = table[xv0 * HH + 16 * (4 * w + nt2) + (l & 15)];
            xv_nn = x[b * LL + 1];
        }
        const int abyte = (l >> 4) * 16;

        __syncthreads();
#pragma unroll 1
        for (int u = 0; u <= LL; ++u) {
            if (u < LL) {
                const char* hcur = (const char*)hb[u & 1];
                if ((l & 15) == 0) {
#pragma unroll
                    for (int kt = 0; kt < 8; ++kt)
                        a[kt] = *(const bf16x8*)(hcur + kt * 64 + abyte);
                }
                // prefetch next xp / next-next x id
                float xpn[4];
                if (u < LL - 1) {
#pragma unroll
                    for (int nt2 = 0; nt2 < 4; ++nt2)
                        xpn[nt2] = table[xv_nn * HH + 16 * (4 * w + nt2) + (l & 15)];
                }
                int xv3 = (u < LL - 2) ? x[b * LL + u + 2] : 0;

                f32x4 acc[4];
#pragma unroll
                for (int nt2 = 0; nt2 < 4; ++nt2)
                    acc[nt2] = (f32x4){xp[nt2], xp[nt2], xp[nt2], xp[nt2]};
#pragma unroll
                for (int kt = 0; kt < 8; ++kt)
#pragma unroll
                    for (int nt2 = 0; nt2 < 4; ++nt2)
                        acc[nt2] = __builtin_amdgcn_mfma_f32_16x16x32_bf16(
                            a[kt], Bf[nt2][kt], acc[nt2], 0, 0, 0);

                unsigned short* hnxt = hb[(u + 1) & 1];
#pragma unroll
                for (int nt2 = 0; nt2 < 4; ++nt2) {
                    float hval = tanh_fast(acc[nt2][0]);  // row 0: lanes 0-15
                    if (l < 16) {
                        hnxt[16 * (4 * w + nt2) + l] = f2bf(hval);
                        if (u == LL - 1)
                            outH[b * HH + 16 * (4 * w + nt2) + l] = hval;
                    }
                }
#pragma unroll
                for (int nt2 = 0; nt2 < 4; ++nt2) xp[nt2] = xpn[nt2];
                xv_nn = xv3;
            }
            __syncthreads();
        }
    } else {
        // ---------------- logits role: waves 4,5 → nt = (w-4)*2 + {0,1} ----------------
        const int nb = (w - 4) * 2;
        bf16x8 FH[2][8], FL[2][8];
#pragma unroll
        for (int nt2 = 0; nt2 < 2; ++nt2)
#pragma unroll
            for (int kt = 0; kt < 8; ++kt) {
                FH[nt2][kt] = *(const bf16x8*)(wsFH + (((nb + nt2) * 8 + kt) * 1024) + l * 16);
                FL[nt2][kt] = *(const bf16x8*)(wsFL + (((nb + nt2) * 8 + kt) * 1024) + l * 16);
            }
        float fcb[2];
#pragma unroll
        for (int nt2 = 0; nt2 < 2; ++nt2)
            fcb[nt2] = fc_b[16 * (nb + nt2) + (l & 15)];

        bf16x8 a[8];
        bf16x8 zz = {0, 0, 0, 0, 0, 0, 0, 0};
#pragma unroll
        for (int kt = 0; kt < 8; ++kt) a[kt] = zz;
        const int abyte = (l >> 4) * 16;

        __syncthreads();
#pragma unroll 1
        for (int u = 0; u <= LL; ++u) {
            if (u >= 1) {
                // hb[u&1] holds h_{u-1}; compute logits for step u-1
                const char* hcur = (const char*)hb[u & 1];
                if ((l & 15) == 0) {
#pragma unroll
                    for (int kt = 0; kt < 8; ++kt)
                        a[kt] = *(const bf16x8*)(hcur + kt * 64 + abyte);
                }
                f32x4 aH[2], aL[2];
#pragma unroll
                for (int nt2 = 0; nt2 < 2; ++nt2) {
                    aH[nt2] = (f32x4){fcb[nt2], fcb[nt2], fcb[nt2], fcb[nt2]};
                    aL[nt2] = (f32x4){0.f, 0.f, 0.f, 0.f};
                }
#pragma unroll
                for (int kt = 0; kt < 8; ++kt)
#pragma unroll
                    for (int nt2 = 0; nt2 < 2; ++nt2) {
                        aH[nt2] = __builtin_amdgcn_mfma_f32_16x16x32_bf16(
                            a[kt], FH[nt2][kt], aH[nt2], 0, 0, 0);
                        aL[nt2] = __builtin_amdgcn_mfma_f32_16x16x32_bf16(
                            a[kt], FL[nt2][kt], aL[nt2], 0, 0, 0);
                    }
                if (l < 16) {
                    const int s = u - 1;
#pragma unroll
                    for (int nt2 = 0; nt2 < 2; ++nt2)
                        outL[((size_t)b * LL + s) * VV + 16 * (nb + nt2) + (l & 15)] =
                            aH[nt2][0] + aL[nt2][0];
                }
            }
            __syncthreads();
        }
    }
}

extern "C" void kernel_launch(void* const* d_in, const int* in_sizes, int n_in,
                              void* d_out, int out_size, void* d_ws, size_t ws_size,
                              hipStream_t stream) {
    const int*   x      = (const int*)  d_in[0];
    const float* hidden = (const float*)d_in[1];
    const float* emb    = (const float*)d_in[2];
    const float* W_e    = (const float*)d_in[3];
    const float* b_e    = (const float*)d_in[4];
    const float* W_h    = (const float*)d_in[5];
    const float* b_h    = (const float*)d_in[6];
    const float* fc_w   = (const float*)d_in[7];
    const float* fc_b   = (const float*)d_in[8];
    float* out = (float*)d_out;
    float* ws  = (float*)d_ws;

    prep_kernel<<<104, 256, 0, stream>>>(emb, W_e, b_e, W_h, b_h, fc_w, ws);
    rnn_kernel<<<BB, 384, 0, stream>>>(x, hidden, fc_b, ws, out);
}